// Round 2
// baseline (6295.314 us; speedup 1.0000x reference)
//
#include <hip/hip_runtime.h>
#include <hip/hip_bf16.h>

#define D_  512
#define H_  8
#define DH_ 64
#define L_  6
#define FF_ 2048
#define V_  4096
#define B_  2
#define S_  4096
#define SB_ (S_*B_)   // 8192 tokens

typedef __hip_bfloat16 bf16;
typedef unsigned short u16;

__device__ __forceinline__ float us2f(u16 u){
  union { unsigned int i; float f; } c; c.i = ((unsigned int)u) << 16; return c.f;
}
// load element i of external tensor p: bf16 if isbf else fp32
__device__ __forceinline__ float ldf(const void* p, size_t i, int isbf){
  return isbf ? us2f(((const u16*)p)[i]) : ((const float*)p)[i];
}

// ---------------------------------------------------------------------------
// dtype sniffer: bf16 data -> every halfword has a sane exponent field;
// fp32 data -> low halfwords are mantissa bits (uniform exponent field).
// ---------------------------------------------------------------------------
__global__ __launch_bounds__(64) void detect_dtype(const void* emb, int* flag)
{
  const int t = threadIdx.x;
  u16 hw = ((const u16*)emb)[t];
  int e = (hw >> 7) & 0xFF;
  int ok = ((e > 96) && (e < 160)) || ((hw & 0x7FFF) == 0);
  unsigned long long m = __ballot(ok);
  if (t == 0) *flag = (__popcll(m) >= 56) ? 1 : 0;
}

// ---------------------------------------------------------------------------
// GEMM (NT): C[m,n] = act( sum_k A[m,k] * W[w_off + n*K + k] + bias[b_off+n]
//                          (+ res[m,n]) )
// A fp32 [M,K] row-major; W external (bf16 or fp32 per flag), row-major [N,K].
// ACT: 0 none, 1 relu. OUT: 0 fp32 C[m*N+n]; 1 scatter out[(b*V+n)*S+s].
// ---------------------------------------------------------------------------
template<int ACT, int OUT>
__global__ __launch_bounds__(256) void gemm_nt(
    const float* A, const void* W, size_t w_off, const void* bias, size_t b_off,
    const float* res, void* Cout, int M, int N, int K, const int* flagp)
{
  __shared__ float As[16][68];   // [k][m]
  __shared__ float Bs[16][68];   // [k][n]
  const int isbf = *flagp;
  const int bm = blockIdx.y << 6, bn = blockIdx.x << 6;
  const int t  = threadIdx.x;
  const int tx = t & 15, ty = t >> 4;        // 16x16 threads, 4x4 micro-tile
  const int lr = t >> 2, lc = (t & 3) << 2;  // loader: row 0..63, k-col {0,4,8,12}
  const float* ap = A + (size_t)(bm + lr) * K + lc;
  const size_t wbase = w_off + (size_t)(bn + lr) * K + lc;
  float acc[4][4] = {};
  for (int k0 = 0; k0 < K; k0 += 16) {
    float4 av = *(const float4*)(ap + k0);
    float4 wv;
    if (isbf) {
      ushort4 u = *(const ushort4*)((const u16*)W + wbase + k0);
      wv = make_float4(us2f(u.x), us2f(u.y), us2f(u.z), us2f(u.w));
    } else {
      wv = *(const float4*)((const float*)W + wbase + k0);
    }
    As[lc+0][lr] = av.x; As[lc+1][lr] = av.y; As[lc+2][lr] = av.z; As[lc+3][lr] = av.w;
    Bs[lc+0][lr] = wv.x; Bs[lc+1][lr] = wv.y; Bs[lc+2][lr] = wv.z; Bs[lc+3][lr] = wv.w;
    __syncthreads();
    #pragma unroll
    for (int kk = 0; kk < 16; kk++) {
      float4 a4 = *(const float4*)&As[kk][ty << 2];
      float4 b4 = *(const float4*)&Bs[kk][tx << 2];
      float aa[4] = {a4.x, a4.y, a4.z, a4.w};
      float bb[4] = {b4.x, b4.y, b4.z, b4.w};
      #pragma unroll
      for (int i = 0; i < 4; i++)
        #pragma unroll
        for (int j = 0; j < 4; j++)
          acc[i][j] += aa[i] * bb[j];
    }
    __syncthreads();
  }
  #pragma unroll
  for (int i = 0; i < 4; i++) {
    const int m = bm + (ty << 2) + i;
    #pragma unroll
    for (int j = 0; j < 4; j++) {
      const int n = bn + (tx << 2) + j;
      float c = acc[i][j] + ldf(bias, b_off + n, isbf);
      if (res) c += res[(size_t)m * N + n];
      if (ACT == 1) c = fmaxf(c, 0.f);
      if (OUT == 0) {
        ((float*)Cout)[(size_t)m * N + n] = c;
      } else {
        const int s = m >> 1, bb2 = m & 1;       // m = s*B + b, B=2
        const size_t oi = ((size_t)bb2 * V_ + n) * S_ + s;
        if (isbf) ((u16*)Cout)[oi] = (u16)(__bfloat16_as_ushort(__float2bfloat16(c)));
        else      ((float*)Cout)[oi] = c;
      }
    }
  }
}

// ---------------------------------------------------------------------------
// unit / unit+elu over contiguous 64-element head vectors, in place.
// ---------------------------------------------------------------------------
template<int ELU>
__global__ __launch_bounds__(256) void unit_k(float* __restrict__ buf)
{
  const int vec  = blockIdx.x * 4 + (threadIdx.x >> 6);
  const int lane = threadIdx.x & 63;
  float* p = buf + (size_t)vec * 64;
  float x = p[lane];
  float ss = x * x;
  #pragma unroll
  for (int off = 32; off >= 1; off >>= 1) ss += __shfl_xor(ss, off);
  float u = x / sqrtf(fmaxf(ss, 1e-30f));
  if (ELU) u = (u > 0.f) ? u : expm1f(u);
  p[lane] = u;
}

// ---------------------------------------------------------------------------
// A[b,n,vi,qi] += sum_{s in chunk} v[s,b,n,vi] * k[s,b,n,qi]
// ---------------------------------------------------------------------------
__global__ __launch_bounds__(256) void attn_accA(
    const float* __restrict__ kbuf, const float* __restrict__ vbuf,
    float* __restrict__ Abuf)
{
  __shared__ float ks[64][64];
  __shared__ float vs[64][64];
  const int bh = blockIdx.x;              // b*H + n
  const int b  = bh >> 3, n = bh & 7;
  const int chunk = blockIdx.y;
  const int t = threadIdx.x;
  const int row = t >> 2, colb = (t & 3) << 4;
  const int vi0 = (t >> 4) << 2, qi0 = (t & 15) << 2;
  float acc[4][4] = {};
  for (int st = 0; st < 4; st++) {
    const int s0 = chunk * 256 + st * 64;
    const size_t g = ((size_t)(s0 + row) * B_ + b) * D_ + n * 64 + colb;
    #pragma unroll
    for (int u = 0; u < 4; u++) {
      *(float4*)&ks[row][colb + 4*u] = *(const float4*)&kbuf[g + 4*u];
      *(float4*)&vs[row][colb + 4*u] = *(const float4*)&vbuf[g + 4*u];
    }
    __syncthreads();
    #pragma unroll 8
    for (int s = 0; s < 64; s++) {
      float kv[4], vv[4];
      #pragma unroll
      for (int j = 0; j < 4; j++) kv[j] = ks[s][qi0 + j];
      #pragma unroll
      for (int i = 0; i < 4; i++) vv[i] = vs[s][vi0 + i];
      #pragma unroll
      for (int i = 0; i < 4; i++)
        #pragma unroll
        for (int j = 0; j < 4; j++)
          acc[i][j] += vv[i] * kv[j];
    }
    __syncthreads();
  }
  float* Ap = Abuf + (size_t)bh * 4096;
  #pragma unroll
  for (int i = 0; i < 4; i++)
    #pragma unroll
    for (int j = 0; j < 4; j++)
      atomicAdd(&Ap[(vi0 + i) * 64 + (qi0 + j)], acc[i][j]);
}

// ---------------------------------------------------------------------------
// o[s,b,n,vi] = sum_qi q[s,b,n,qi] * A[b,n,vi,qi]; overwrites q with o.
// ---------------------------------------------------------------------------
__global__ __launch_bounds__(256) void attn_applyA(
    float* __restrict__ qo, const float* __restrict__ Abuf)
{
  const int sb   = blockIdx.x;
  const int wave = threadIdx.x >> 6, lane = threadIdx.x & 63;
  const int b = sb & 1;
  #pragma unroll
  for (int h2 = 0; h2 < 2; h2++) {
    const int n = wave * 2 + h2;
    const float* Ah = Abuf + ((size_t)(b * H_ + n)) * 4096 + lane * 64;
    float* qp = qo + (size_t)sb * D_ + n * 64;
    const float qv = qp[lane];
    float acc = 0.f;
    #pragma unroll 8
    for (int qi = 0; qi < 64; qi++)
      acc += __shfl(qv, qi) * Ah[qi];
    qp[lane] = acc;
  }
}

// ---------------------------------------------------------------------------
// LayerNorm in place over D=512 per token.
// ---------------------------------------------------------------------------
__global__ __launch_bounds__(256) void ln_inplace(
    float* __restrict__ h, const void* g, size_t g_off,
    const void* be, size_t be_off, const int* flagp)
{
  const int isbf = *flagp;
  const int m = blockIdx.x, t = threadIdx.x;
  float* p = h + (size_t)m * D_;
  const float x0 = p[t], x1 = p[t + 256];
  __shared__ float red[4];
  float s = x0 + x1;
  #pragma unroll
  for (int off = 32; off >= 1; off >>= 1) s += __shfl_xor(s, off);
  if ((t & 63) == 0) red[t >> 6] = s;
  __syncthreads();
  const float mean = (red[0] + red[1] + red[2] + red[3]) * (1.f / 512.f);
  const float d0 = x0 - mean, d1 = x1 - mean;
  float s2 = d0 * d0 + d1 * d1;
  #pragma unroll
  for (int off = 32; off >= 1; off >>= 1) s2 += __shfl_xor(s2, off);
  __syncthreads();
  if ((t & 63) == 0) red[t >> 6] = s2;
  __syncthreads();
  const float var = (red[0] + red[1] + red[2] + red[3]) * (1.f / 512.f);
  const float sc = rsqrtf(var + 1e-5f);
  p[t]       = d0 * sc * ldf(g, g_off + t, isbf)       + ldf(be, be_off + t, isbf);
  p[t + 256] = d1 * sc * ldf(g, g_off + t + 256, isbf) + ldf(be, be_off + t + 256, isbf);
}

// h[(s*B+b)*D + d] = emb[input[b*S+s]*D + d]
__global__ __launch_bounds__(512) void embed_k(
    const int* __restrict__ inp, const void* emb, float* __restrict__ h,
    const int* flagp)
{
  const int isbf = *flagp;
  const int m = blockIdx.x, t = threadIdx.x;   // m = s*B + b
  const int s = m >> 1, b = m & 1;
  const int tok = inp[b * S_ + s];
  h[(size_t)m * D_ + t] = ldf(emb, (size_t)tok * D_ + t, isbf);
}

__global__ __launch_bounds__(256) void zero_f(float* __restrict__ p, int n)
{
  const int i = blockIdx.x * 256 + threadIdx.x;
  if (i < n) p[i] = 0.f;
}

// ---------------------------------------------------------------------------
extern "C" void kernel_launch(void* const* d_in, const int* in_sizes, int n_in,
                              void* d_out, int out_size, void* d_ws, size_t ws_size,
                              hipStream_t stream) {
  const int*  inp = (const int*) d_in[0];
  const void* emb = d_in[1];
  const void* Wq  = d_in[2];
  const void* bq  = d_in[3];
  const void* Wk  = d_in[4];
  const void* bk  = d_in[5];
  const void* Wv  = d_in[6];
  const void* bv  = d_in[7];
  const void* Wo  = d_in[8];
  const void* bo  = d_in[9];
  const void* W1  = d_in[10];
  const void* b1  = d_in[11];
  const void* W2  = d_in[12];
  const void* b2  = d_in[13];
  const void* g2  = d_in[14];
  const void* be2 = d_in[15];
  const void* Wfc = d_in[16];
  const void* bfc = d_in[17];

  // workspace layout (floats); mid aliases q/k/v (dead by FFN time)
  float* ws  = (float*)d_ws;
  float* h   = ws;                                   // 4.19M
  float* qb  = ws +  4194304;                        // 4.19M
  float* kb  = ws +  8388608;                        // 4.19M
  float* vb  = ws + 12582912;                        // 4.19M
  float* mid = ws +  4194304;                        // 16.78M (aliases q,k,v)
  float* Ab  = ws + 20971520;                        // 65536
  int*  flag = (int*)(ws + 21037056);
  const int nA = B_ * H_ * DH_ * DH_;                // 65536

  detect_dtype<<<1, 64, 0, stream>>>(emb, flag);
  embed_k<<<SB_, 512, 0, stream>>>(inp, emb, h, flag);

  const size_t dd = (size_t)D_ * D_, fd = (size_t)FF_ * D_;
  for (int l = 0; l < L_; l++) {
    dim3 gD(D_ / 64, SB_ / 64), gF(FF_ / 64, SB_ / 64);
    gemm_nt<0,0><<<gD, 256, 0, stream>>>(h, Wq, l*dd, bq, (size_t)l*D_, nullptr, qb, SB_, D_, D_, flag);
    gemm_nt<0,0><<<gD, 256, 0, stream>>>(h, Wk, l*dd, bk, (size_t)l*D_, nullptr, kb, SB_, D_, D_, flag);
    gemm_nt<0,0><<<gD, 256, 0, stream>>>(h, Wv, l*dd, bv, (size_t)l*D_, nullptr, vb, SB_, D_, D_, flag);

    unit_k<1><<<SB_ * H_ / 4, 256, 0, stream>>>(kb);   // k = elu(unit(k))
    unit_k<0><<<SB_ * H_ / 4, 256, 0, stream>>>(qb);   // q = unit(q)

    zero_f<<<(nA + 255) / 256, 256, 0, stream>>>(Ab, nA);
    attn_accA<<<dim3(B_ * H_, S_ / 256), 256, 0, stream>>>(kb, vb, Ab);
    attn_applyA<<<SB_, 256, 0, stream>>>(qb, Ab);      // qb now holds o

    // h += o @ Wo^T + bo
    gemm_nt<0,0><<<gD, 256, 0, stream>>>(qb, Wo, l*dd, bo, (size_t)l*D_, h, h, SB_, D_, D_, flag);
    // mid = relu(h @ W1^T + b1)   (mid clobbers q/k/v — all dead now)
    gemm_nt<1,0><<<gF, 256, 0, stream>>>(h, W1, l*fd, b1, (size_t)l*FF_, nullptr, mid, SB_, FF_, D_, flag);
    // h = h + mid @ W2^T + b2, then LN in place
    gemm_nt<0,0><<<gD, 256, 0, stream>>>(mid, W2, l*fd, b2, (size_t)l*D_, h, h, SB_, D_, FF_, flag);
    ln_inplace<<<SB_, 256, 0, stream>>>(h, g2, (size_t)l*D_, be2, (size_t)l*D_, flag);
  }

  // out[b,v,s] = h[s,b,:] @ Wfc[v,:] + bfc[v]
  gemm_nt<0,1><<<dim3(V_ / 64, SB_ / 64), 256, 0, stream>>>(
      h, Wfc, 0, bfc, 0, nullptr, d_out, SB_, V_, D_, flag);
}

// Round 4
// 2793.767 us; speedup vs baseline: 2.2533x; 2.2533x over previous
//
#include <hip/hip_runtime.h>
#include <hip/hip_bf16.h>

#define D_  512
#define H_  8
#define DH_ 64
#define L_  6
#define FF_ 2048
#define V_  4096
#define B_  2
#define S_  4096
#define SB_ (S_*B_)   // 8192 tokens
#define DD_ ((size_t)D_*D_)
#define FD_ ((size_t)FF_*D_)

typedef unsigned short u16;
typedef unsigned int   u32;
typedef _Float16 f16;
typedef f16   f16x8 __attribute__((ext_vector_type(8)));
typedef float f32x4 __attribute__((ext_vector_type(4)));

__device__ __forceinline__ float us2f(u16 u){          // bf16 bits -> float
  union { u32 i; float f; } c; c.i = ((u32)u) << 16; return c.f;
}
__device__ __forceinline__ u16 f2b(float f){           // float -> bf16 bits (RNE)
  union { float f; u32 i; } c; c.f = f;
  u32 x = c.i;
  x += 0x7FFF + ((x >> 16) & 1);
  return (u16)(x >> 16);
}
__device__ __forceinline__ float h2f(u16 u){           // fp16 bits -> float
  union { u16 s; f16 h; } c; c.s = u; return (float)c.h;
}
__device__ __forceinline__ u16 f2h(float f){           // float -> fp16 bits (RNE)
  union { f16 h; u16 s; } c; c.h = (f16)f; return c.s;
}
// load element i of external tensor p: bf16 if isbf else fp32
__device__ __forceinline__ float ldf(const void* p, size_t i, int isbf){
  return isbf ? us2f(((const u16*)p)[i]) : ((const float*)p)[i];
}

typedef const __attribute__((address_space(1))) u32* gas_u32p;
typedef       __attribute__((address_space(3))) u32* las_u32p;
// async 16B/lane global->LDS; LDS dest = wave-uniform base + lane*16
__device__ __forceinline__ void async16(const u16* g, u16* l){
  __builtin_amdgcn_global_load_lds((gas_u32p)(const void*)g, (las_u32p)(void*)l, 16, 0, 0);
}

// ---------------------------------------------------------------------------
// dtype sniffer (empirically: inputs are fp32 -> flag 0; kept for robustness)
// ---------------------------------------------------------------------------
__global__ __launch_bounds__(64) void detect_dtype(const void* emb, int* flag)
{
  const int t = threadIdx.x;
  u16 hw = ((const u16*)emb)[t];
  int e = (hw >> 7) & 0xFF;
  int ok = ((e > 96) && (e < 160)) || ((hw & 0x7FFF) == 0);
  unsigned long long m = __ballot(ok);
  if (t == 0) *flag = (__popcll(m) >= 56) ? 1 : 0;
}

// ---------------------------------------------------------------------------
// convert one layer's 6 weight matrices to fp16 into dst [q|k|v|o|W1|W2]
// ---------------------------------------------------------------------------
__global__ __launch_bounds__(256) void cvt_layer(
    const void* Wq, const void* Wk, const void* Wv, const void* Wo,
    const void* W1, const void* W2, int l, u16* __restrict__ dst, const int* flagp)
{
  const int isbf = *flagp;
  const size_t i = ((size_t)blockIdx.x * 256 + threadIdx.x) * 4;
  const size_t n4 = 4 * DD_, nW1 = n4 + FD_, nTot = n4 + 2 * FD_;
  if (i >= nTot) return;
  const void* src; size_t off;
  if (i < n4) {
    const int wsel = (int)(i / DD_);
    src = (wsel == 0) ? Wq : (wsel == 1) ? Wk : (wsel == 2) ? Wv : Wo;
    off = (size_t)l * DD_ + (i - (size_t)wsel * DD_);
  } else if (i < nW1) { src = W1; off = (size_t)l * FD_ + (i - n4); }
  else                { src = W2; off = (size_t)l * FD_ + (i - nW1); }
  ushort4 o;
  if (isbf) {
    ushort4 u = *(const ushort4*)((const u16*)src + off);
    o = make_ushort4(f2h(us2f(u.x)), f2h(us2f(u.y)), f2h(us2f(u.z)), f2h(us2f(u.w)));
  } else {
    float4 f = *(const float4*)((const float*)src + off);
    o = make_ushort4(f2h(f.x), f2h(f.y), f2h(f.z), f2h(f.w));
  }
  *(ushort4*)&dst[i] = o;
}

__global__ __launch_bounds__(256) void cvt1(
    const void* src, u16* __restrict__ dst, size_t n, const int* flagp)
{
  const int isbf = *flagp;
  const size_t i = ((size_t)blockIdx.x * 256 + threadIdx.x) * 4;
  if (i >= n) return;
  ushort4 o;
  if (isbf) {
    ushort4 u = *(const ushort4*)((const u16*)src + i);
    o = make_ushort4(f2h(us2f(u.x)), f2h(us2f(u.y)), f2h(us2f(u.z)), f2h(us2f(u.w)));
  } else {
    float4 f = *(const float4*)((const float*)src + i);
    o = make_ushort4(f2h(f.x), f2h(f.y), f2h(f.z), f2h(f.w));
  }
  *(ushort4*)&dst[i] = o;
}

// ---------------------------------------------------------------------------
// MFMA GEMM (fp16 operands, fp32 accumulate):
//  C[m,n] = epilogue( sum_k A[m,k] * B[brow(n),k] + bias )
//  A fp16 [M,K] rows; B fp16, row index = (bn+n)*bstride + boff (weights: 1,0)
//  128x128 tile, BK=32, 4 waves, 16x16x32 f16 MFMA, global_load_lds x16B.
//  OUTMODE 0: fp16 Cb[m*N+n]                       (+ relu if ACT)
//  OUTMODE 1: fp32 Cf and fp16 Cb, res added       (residual update)
//  OUTMODE 3: flag-dtype Cout[out_base+m*N+n], bias per-m  (FC, transposed)
//  OUTMODE 4: unit-normalize per 64-wide head, fp16 Cb (+ elu if ACT)
// ---------------------------------------------------------------------------
template<int ACT, int OUTMODE>
__global__ __launch_bounds__(256) void gemm_mfma(
    const u16* __restrict__ A, const u16* __restrict__ Bm,
    int bstride, int boff,
    const void* bias, size_t bias_off,
    const float* __restrict__ res,
    float* __restrict__ Cf, u16* __restrict__ Cb,
    void* __restrict__ Cout, size_t out_base,
    int M, int N, int K, const int* flagp)
{
  __shared__ u16 tile[8192];              // A: [0,4096) elts, B: [4096,8192)
  const int t = threadIdx.x, lane = t & 63, w = t >> 6;
  const int bm = blockIdx.y << 7, bn = blockIdx.x << 7;
  const int wr = w >> 1, wc = w & 1;
  const int col = lane & 15, quad = lane >> 4;

  // staging: each wave fills 1024B per call; lane covers 16B
  const int srow = w * 16 + (lane >> 2);  // row 0..63 (+64 for second half)
  const int skol = (lane & 3) << 3;       // k element offset
  const u16* ag0 = A + (size_t)(bm + srow) * K + skol;
  const u16* ag1 = A + (size_t)(bm + 64 + srow) * K + skol;
  const u16* bg0 = Bm + ((size_t)(bn + srow) * bstride + boff) * K + skol;
  const u16* bg1 = Bm + ((size_t)(bn + 64 + srow) * bstride + boff) * K + skol;
  u16* la0 = &tile[       w * 512];
  u16* la1 = &tile[2048 + w * 512];
  u16* lb0 = &tile[4096 + w * 512];
  u16* lb1 = &tile[6144 + w * 512];

  f32x4 acc[4][4] = {};
  for (int k0 = 0; k0 < K; k0 += 32) {
    async16(ag0 + k0, la0);
    async16(ag1 + k0, la1);
    async16(bg0 + k0, lb0);
    async16(bg1 + k0, lb1);
    __syncthreads();                      // vmcnt(0) drain + barrier
    f16x8 af[4], bf[4];
    #pragma unroll
    for (int i = 0; i < 4; i++)
      af[i] = *(const f16x8*)&tile[(wr * 64 + i * 16 + col) * 32 + quad * 8];
    #pragma unroll
    for (int j = 0; j < 4; j++)
      bf[j] = *(const f16x8*)&tile[4096 + (wc * 64 + j * 16 + col) * 32 + quad * 8];
    #pragma unroll
    for (int i = 0; i < 4; i++)
      #pragma unroll
      for (int j = 0; j < 4; j++)
        acc[i][j] = __builtin_amdgcn_mfma_f32_16x16x32_f16(af[i], bf[j], acc[i][j], 0, 0, 0);
    __syncthreads();                      // protect LDS before next stores
  }

  const int isbf = *flagp;
  if (OUTMODE == 4) {
    // C/D layout: n = bn + wc*64 + j*16 + col, m = bm + wr*64 + i*16 + quad*4 + r
    // head = the 64 cols owned by this wave-column; reduce over j and 16 cols.
    #pragma unroll
    for (int i = 0; i < 4; i++) {
      #pragma unroll
      for (int r = 0; r < 4; r++) {
        float v[4]; float ss = 0.f;
        #pragma unroll
        for (int j = 0; j < 4; j++) {
          const int n = bn + wc * 64 + j * 16 + col;
          v[j] = acc[i][j][r] + ldf(bias, bias_off + n, isbf);
          ss += v[j] * v[j];
        }
        ss += __shfl_xor(ss, 1); ss += __shfl_xor(ss, 2);
        ss += __shfl_xor(ss, 4); ss += __shfl_xor(ss, 8);
        const float inv = rsqrtf(fmaxf(ss, 1e-30f));
        const int m = bm + wr * 64 + i * 16 + quad * 4 + r;
        #pragma unroll
        for (int j = 0; j < 4; j++) {
          float u = v[j] * inv;
          if (ACT) u = (u > 0.f) ? u : expm1f(u);
          const int n = bn + wc * 64 + j * 16 + col;
          Cb[(size_t)m * N + n] = f2h(u);
        }
      }
    }
  } else {
    #pragma unroll
    for (int i = 0; i < 4; i++) {
      #pragma unroll
      for (int r = 0; r < 4; r++) {
        const int m = bm + wr * 64 + i * 16 + quad * 4 + r;
        #pragma unroll
        for (int j = 0; j < 4; j++) {
          const int n = bn + wc * 64 + j * 16 + col;
          float c = acc[i][j][r];
          if (OUTMODE == 3) c += ldf(bias, bias_off + m, isbf);
          else              c += ldf(bias, bias_off + n, isbf);
          if (res) c += res[(size_t)m * N + n];
          if (ACT == 1 && OUTMODE != 4) c = fmaxf(c, 0.f);
          if (OUTMODE == 0) {
            Cb[(size_t)m * N + n] = f2h(c);
          } else if (OUTMODE == 1) {
            Cf[(size_t)m * N + n] = c;
            Cb[(size_t)m * N + n] = f2h(c);
          } else {
            const size_t oi = out_base + (size_t)m * N + n;
            if (isbf) ((u16*)Cout)[oi] = f2b(c);
            else      ((float*)Cout)[oi] = c;
          }
        }
      }
    }
  }
}

// ---------------------------------------------------------------------------
// A[b,n,vi,qi] += sum_{s in chunk} v[s,b,n,vi] * k[s,b,n,qi]   (fp16 in)
// ---------------------------------------------------------------------------
__global__ __launch_bounds__(256) void attn_accA(
    const u16* __restrict__ kbuf, const u16* __restrict__ vbuf,
    float* __restrict__ Abuf)
{
  __shared__ float ks[64][64];
  __shared__ float vs[64][64];
  const int bh = blockIdx.x;              // b*H + n
  const int b  = bh >> 3, n = bh & 7;
  const int chunk = blockIdx.y;
  const int t = threadIdx.x;
  const int row = t >> 2, colb = (t & 3) << 4;
  const int vi0 = (t >> 4) << 2, qi0 = (t & 15) << 2;
  float acc[4][4] = {};
  for (int st = 0; st < 4; st++) {
    const int s0 = chunk * 256 + st * 64;
    const size_t g = ((size_t)(s0 + row) * B_ + b) * D_ + n * 64 + colb;
    #pragma unroll
    for (int u = 0; u < 4; u++) {
      ushort4 kk = *(const ushort4*)&kbuf[g + 4*u];
      ushort4 vv = *(const ushort4*)&vbuf[g + 4*u];
      ks[row][colb+4*u+0] = h2f(kk.x); ks[row][colb+4*u+1] = h2f(kk.y);
      ks[row][colb+4*u+2] = h2f(kk.z); ks[row][colb+4*u+3] = h2f(kk.w);
      vs[row][colb+4*u+0] = h2f(vv.x); vs[row][colb+4*u+1] = h2f(vv.y);
      vs[row][colb+4*u+2] = h2f(vv.z); vs[row][colb+4*u+3] = h2f(vv.w);
    }
    __syncthreads();
    #pragma unroll 8
    for (int s = 0; s < 64; s++) {
      float kv[4], vv[4];
      #pragma unroll
      for (int j = 0; j < 4; j++) kv[j] = ks[s][qi0 + j];
      #pragma unroll
      for (int i = 0; i < 4; i++) vv[i] = vs[s][vi0 + i];
      #pragma unroll
      for (int i = 0; i < 4; i++)
        #pragma unroll
        for (int j = 0; j < 4; j++)
          acc[i][j] += vv[i] * kv[j];
    }
    __syncthreads();
  }
  float* Ap = Abuf + (size_t)bh * 4096;
  #pragma unroll
  for (int i = 0; i < 4; i++)
    #pragma unroll
    for (int j = 0; j < 4; j++)
      atomicAdd(&Ap[(vi0 + i) * 64 + (qi0 + j)], acc[i][j]);
}

// ---------------------------------------------------------------------------
// o[s,b,n,vi] = sum_qi q[s,b,n,qi] * A[b,n,vi,qi]; overwrites q (fp16).
// ---------------------------------------------------------------------------
__global__ __launch_bounds__(256) void attn_applyA(
    u16* __restrict__ qo, const float* __restrict__ Abuf)
{
  const int sb   = blockIdx.x;
  const int wave = threadIdx.x >> 6, lane = threadIdx.x & 63;
  const int b = sb & 1;
  #pragma unroll
  for (int h2 = 0; h2 < 2; h2++) {
    const int n = wave * 2 + h2;
    const float* Ah = Abuf + ((size_t)(b * H_ + n)) * 4096 + lane * 64;
    u16* qp = qo + (size_t)sb * D_ + n * 64;
    const float qv = h2f(qp[lane]);
    float acc = 0.f;
    #pragma unroll 8
    for (int qi = 0; qi < 64; qi++)
      acc += __shfl(qv, qi) * Ah[qi];
    qp[lane] = f2h(acc);
  }
}

// ---------------------------------------------------------------------------
// LayerNorm over D=512 per token; reads h fp32, writes h fp32 + hb fp16.
// ---------------------------------------------------------------------------
__global__ __launch_bounds__(256) void ln_k(
    float* __restrict__ h, u16* __restrict__ hb,
    const void* g, size_t g_off, const void* be, size_t be_off, const int* flagp)
{
  const int isbf = *flagp;
  const int m = blockIdx.x, t = threadIdx.x;
  float* p = h + (size_t)m * D_;
  const float x0 = p[t], x1 = p[t + 256];
  __shared__ float red[4];
  float s = x0 + x1;
  #pragma unroll
  for (int off = 32; off >= 1; off >>= 1) s += __shfl_xor(s, off);
  if ((t & 63) == 0) red[t >> 6] = s;
  __syncthreads();
  const float mean = (red[0] + red[1] + red[2] + red[3]) * (1.f / 512.f);
  const float d0 = x0 - mean, d1 = x1 - mean;
  float s2 = d0 * d0 + d1 * d1;
  #pragma unroll
  for (int off = 32; off >= 1; off >>= 1) s2 += __shfl_xor(s2, off);
  __syncthreads();
  if ((t & 63) == 0) red[t >> 6] = s2;
  __syncthreads();
  const float var = (red[0] + red[1] + red[2] + red[3]) * (1.f / 512.f);
  const float sc = rsqrtf(var + 1e-5f);
  const float y0 = d0 * sc * ldf(g, g_off + t, isbf)       + ldf(be, be_off + t, isbf);
  const float y1 = d1 * sc * ldf(g, g_off + t + 256, isbf) + ldf(be, be_off + t + 256, isbf);
  p[t] = y0;       p[t + 256] = y1;
  hb[(size_t)m * D_ + t] = f2h(y0);
  hb[(size_t)m * D_ + t + 256] = f2h(y1);
}

// h/hb[(s*B+b)*D + d] = emb[input[b*S+s]*D + d]
__global__ __launch_bounds__(512) void embed_k(
    const int* __restrict__ inp, const void* emb,
    float* __restrict__ h, u16* __restrict__ hb, const int* flagp)
{
  const int isbf = *flagp;
  const int m = blockIdx.x, t = threadIdx.x;   // m = s*B + b
  const int s = m >> 1, b = m & 1;
  const int tok = inp[b * S_ + s];
  const float v = ldf(emb, (size_t)tok * D_ + t, isbf);
  h[(size_t)m * D_ + t] = v;
  hb[(size_t)m * D_ + t] = f2h(v);
}

__global__ __launch_bounds__(256) void zero_f(float* __restrict__ p, int n)
{
  const int i = blockIdx.x * 256 + threadIdx.x;
  if (i < n) p[i] = 0.f;
}

// ---------------------------------------------------------------------------
extern "C" void kernel_launch(void* const* d_in, const int* in_sizes, int n_in,
                              void* d_out, int out_size, void* d_ws, size_t ws_size,
                              hipStream_t stream) {
  const int*  inp = (const int*) d_in[0];
  const void* emb = d_in[1];
  const void* Wq  = d_in[2];
  const void* bq  = d_in[3];
  const void* Wk  = d_in[4];
  const void* bk  = d_in[5];
  const void* Wv  = d_in[6];
  const void* bv  = d_in[7];
  const void* Wo  = d_in[8];
  const void* bo  = d_in[9];
  const void* W1  = d_in[10];
  const void* b1  = d_in[11];
  const void* W2  = d_in[12];
  const void* b2  = d_in[13];
  const void* g2  = d_in[14];
  const void* be2 = d_in[15];
  const void* Wfc = d_in[16];
  const void* bfc = d_in[17];

  // workspace layout (bytes): mid aliases qb..58720256 (contiguous 33.55 MB)
  char* ws = (char*)d_ws;
  float* h    = (float*)(ws);                    // 16,777,216 B
  u16*   hb   = (u16*)  (ws + 16777216);         //  8,388,608 B (fp16)
  u16*   qb   = (u16*)  (ws + 25165824);         //  8,388,608 B
  u16*   kb   = (u16*)  (ws + 33554432);         //  8,388,608 B
  u16*   vb   = (u16*)  (ws + 41943040);         //  8,388,608 B
  u16*   mid  = qb;                              // 33,554,432 B (qb..58720256)
  float* Ab   = (float*)(ws + 58720256);         //    262,144 B
  u16*   Wc   = (u16*)  (ws + 58982400);         //  6,291,456 B
  int*   flag = (int*)  (ws + 65273856);
  const int nA = B_ * H_ * DH_ * DH_;            // 65536

  detect_dtype<<<1, 64, 0, stream>>>(emb, flag);
  embed_k<<<SB_, 512, 0, stream>>>(inp, emb, h, hb, flag);

  const dim3 gQ(D_ / 128, SB_ / 128);    // (4, 64)
  const dim3 gF(FF_ / 128, SB_ / 128);   // (16, 64)
  const dim3 gFC(S_ / 128, V_ / 128);    // (32, 32)

  for (int l = 0; l < L_; l++) {
    cvt_layer<<<3072, 256, 0, stream>>>(Wq, Wk, Wv, Wo, W1, W2, l, Wc, flag);

    // q = unit(h@Wq^T+bq), k = elu(unit(h@Wk^T+bk)), v = h@Wv^T+bv
    gemm_mfma<0,4><<<gQ, 256, 0, stream>>>(hb, Wc,           1, 0, bq, (size_t)l*D_,  nullptr, nullptr, qb, nullptr, 0, SB_, D_, D_, flag);
    gemm_mfma<1,4><<<gQ, 256, 0, stream>>>(hb, Wc + DD_,     1, 0, bk, (size_t)l*D_,  nullptr, nullptr, kb, nullptr, 0, SB_, D_, D_, flag);
    gemm_mfma<0,0><<<gQ, 256, 0, stream>>>(hb, Wc + 2*DD_,   1, 0, bv, (size_t)l*D_,  nullptr, nullptr, vb, nullptr, 0, SB_, D_, D_, flag);

    zero_f<<<(nA + 255) / 256, 256, 0, stream>>>(Ab, nA);
    attn_accA<<<dim3(B_ * H_, S_ / 256), 256, 0, stream>>>(kb, vb, Ab);
    attn_applyA<<<SB_, 256, 0, stream>>>(qb, Ab);      // qb now holds o (fp16)

    // h += o @ Wo^T + bo  (writes h fp32 + hb fp16)
    gemm_mfma<0,1><<<gQ, 256, 0, stream>>>(qb, Wc + 3*DD_,   1, 0, bo, (size_t)l*D_,  h, h, hb, nullptr, 0, SB_, D_, D_, flag);
    // mid = relu(h @ W1^T + b1)
    gemm_mfma<1,0><<<gF, 256, 0, stream>>>(hb, Wc + 4*DD_,   1, 0, b1, (size_t)l*FF_, nullptr, nullptr, mid, nullptr, 0, SB_, FF_, D_, flag);
    // h = h + mid @ W2^T + b2 (fp32; hb rewritten by LN)
    gemm_mfma<0,1><<<gQ, 256, 0, stream>>>(mid, Wc + 4*DD_ + FD_, 1, 0, b2, (size_t)l*D_, h, h, hb, nullptr, 0, SB_, D_, FF_, flag);
    ln_k<<<SB_, 256, 0, stream>>>(h, hb, g2, (size_t)l*D_, be2, (size_t)l*D_, flag);
  }

  // FC transposed: out[b][v][s] = Wfc[v,:] . hb[s*2+b,:] + bfc[v]
  cvt1<<<2048, 256, 0, stream>>>(Wfc, Wc, (size_t)V_ * D_, flag);
  gemm_mfma<0,3><<<gFC, 256, 0, stream>>>(Wc, hb, 2, 0, bfc, 0, nullptr, nullptr, nullptr, d_out, 0,                 V_, S_, D_, flag);
  gemm_mfma<0,3><<<gFC, 256, 0, stream>>>(Wc, hb, 2, 1, bfc, 0, nullptr, nullptr, nullptr, d_out, (size_t)V_ * S_, V_, S_, D_, flag);
}

// Round 5
// 1966.277 us; speedup vs baseline: 3.2016x; 1.4208x over previous
//
#include <hip/hip_runtime.h>
#include <hip/hip_bf16.h>

#define D_  512
#define H_  8
#define DH_ 64
#define L_  6
#define FF_ 2048
#define V_  4096
#define B_  2
#define S_  4096
#define SB_ (S_*B_)   // 8192 tokens
#define DD_ ((size_t)D_*D_)
#define FD_ ((size_t)FF_*D_)

typedef unsigned short u16;
typedef unsigned int   u32;
typedef _Float16 f16;
typedef f16   f16x8 __attribute__((ext_vector_type(8)));
typedef float f32x4 __attribute__((ext_vector_type(4)));

__device__ __forceinline__ float us2f(u16 u){          // bf16 bits -> float
  union { u32 i; float f; } c; c.i = ((u32)u) << 16; return c.f;
}
__device__ __forceinline__ u16 f2b(float f){           // float -> bf16 bits (RNE)
  union { float f; u32 i; } c; c.f = f;
  u32 x = c.i;
  x += 0x7FFF + ((x >> 16) & 1);
  return (u16)(x >> 16);
}
__device__ __forceinline__ float h2f(u16 u){           // fp16 bits -> float
  union { u16 s; f16 h; } c; c.s = u; return (float)c.h;
}
__device__ __forceinline__ u16 f2h(float f){           // float -> fp16 bits (RNE)
  union { f16 h; u16 s; } c; c.h = (f16)f; return c.s;
}
// load element i of external tensor p: bf16 if isbf else fp32
__device__ __forceinline__ float ldf(const void* p, size_t i, int isbf){
  return isbf ? us2f(((const u16*)p)[i]) : ((const float*)p)[i];
}

typedef const __attribute__((address_space(1))) u32* gas_u32p;
typedef       __attribute__((address_space(3))) u32* las_u32p;
// async 16B/lane global->LDS; LDS dest = wave-uniform base + lane*16
__device__ __forceinline__ void async16(const u16* g, u16* l){
  __builtin_amdgcn_global_load_lds((gas_u32p)(const void*)g, (las_u32p)(void*)l, 16, 0, 0);
}

// ---------------------------------------------------------------------------
// dtype sniffer (empirically: inputs are fp32 -> flag 0; kept for robustness)
// ---------------------------------------------------------------------------
__global__ __launch_bounds__(64) void detect_dtype(const void* emb, int* flag)
{
  const int t = threadIdx.x;
  u16 hw = ((const u16*)emb)[t];
  int e = (hw >> 7) & 0xFF;
  int ok = ((e > 96) && (e < 160)) || ((hw & 0x7FFF) == 0);
  unsigned long long m = __ballot(ok);
  if (t == 0) *flag = (__popcll(m) >= 56) ? 1 : 0;
}

// ---------------------------------------------------------------------------
// convert one layer's 6 weight matrices to fp16 into dst [q|k|v|o|W1|W2]
// ---------------------------------------------------------------------------
__global__ __launch_bounds__(256) void cvt_layer(
    const void* Wq, const void* Wk, const void* Wv, const void* Wo,
    const void* W1, const void* W2, int l, u16* __restrict__ dst, const int* flagp)
{
  const int isbf = *flagp;
  const size_t i = ((size_t)blockIdx.x * 256 + threadIdx.x) * 4;
  const size_t n4 = 4 * DD_, nW1 = n4 + FD_, nTot = n4 + 2 * FD_;
  if (i >= nTot) return;
  const void* src; size_t off;
  if (i < n4) {
    const int wsel = (int)(i / DD_);
    src = (wsel == 0) ? Wq : (wsel == 1) ? Wk : (wsel == 2) ? Wv : Wo;
    off = (size_t)l * DD_ + (i - (size_t)wsel * DD_);
  } else if (i < nW1) { src = W1; off = (size_t)l * FD_ + (i - n4); }
  else                { src = W2; off = (size_t)l * FD_ + (i - nW1); }
  ushort4 o;
  if (isbf) {
    ushort4 u = *(const ushort4*)((const u16*)src + off);
    o = make_ushort4(f2h(us2f(u.x)), f2h(us2f(u.y)), f2h(us2f(u.z)), f2h(us2f(u.w)));
  } else {
    float4 f = *(const float4*)((const float*)src + off);
    o = make_ushort4(f2h(f.x), f2h(f.y), f2h(f.z), f2h(f.w));
  }
  *(ushort4*)&dst[i] = o;
}

__global__ __launch_bounds__(256) void cvt1(
    const void* src, u16* __restrict__ dst, size_t n, const int* flagp)
{
  const int isbf = *flagp;
  const size_t i = ((size_t)blockIdx.x * 256 + threadIdx.x) * 4;
  if (i >= n) return;
  ushort4 o;
  if (isbf) {
    ushort4 u = *(const ushort4*)((const u16*)src + i);
    o = make_ushort4(f2h(us2f(u.x)), f2h(us2f(u.y)), f2h(us2f(u.z)), f2h(us2f(u.w)));
  } else {
    float4 f = *(const float4*)((const float*)src + i);
    o = make_ushort4(f2h(f.x), f2h(f.y), f2h(f.z), f2h(f.w));
  }
  *(ushort4*)&dst[i] = o;
}

// ---------------------------------------------------------------------------
// MFMA GEMM (fp16 operands, fp32 accumulate):  (unchanged from R4 — validated)
//  C[m,n] = epilogue( sum_k A[m,k] * B[brow(n),k] + bias )
//  OUTMODE 0: fp16 Cb[m*N+n] (+relu)  1: fp32 Cf + fp16 Cb, res added
//  3: flag-dtype Cout[out_base+m*N+n], bias per-m   4: unit per head (+elu)
// ---------------------------------------------------------------------------
template<int ACT, int OUTMODE>
__global__ __launch_bounds__(256) void gemm_mfma(
    const u16* __restrict__ A, const u16* __restrict__ Bm,
    int bstride, int boff,
    const void* bias, size_t bias_off,
    const float* __restrict__ res,
    float* __restrict__ Cf, u16* __restrict__ Cb,
    void* __restrict__ Cout, size_t out_base,
    int M, int N, int K, const int* flagp)
{
  __shared__ u16 tile[8192];              // A: [0,4096) elts, B: [4096,8192)
  const int t = threadIdx.x, lane = t & 63, w = t >> 6;
  const int bm = blockIdx.y << 7, bn = blockIdx.x << 7;
  const int wr = w >> 1, wc = w & 1;
  const int col = lane & 15, quad = lane >> 4;

  const int srow = w * 16 + (lane >> 2);  // row 0..63 (+64 for second half)
  const int skol = (lane & 3) << 3;       // k element offset
  const u16* ag0 = A + (size_t)(bm + srow) * K + skol;
  const u16* ag1 = A + (size_t)(bm + 64 + srow) * K + skol;
  const u16* bg0 = Bm + ((size_t)(bn + srow) * bstride + boff) * K + skol;
  const u16* bg1 = Bm + ((size_t)(bn + 64 + srow) * bstride + boff) * K + skol;
  u16* la0 = &tile[       w * 512];
  u16* la1 = &tile[2048 + w * 512];
  u16* lb0 = &tile[4096 + w * 512];
  u16* lb1 = &tile[6144 + w * 512];

  f32x4 acc[4][4] = {};
  for (int k0 = 0; k0 < K; k0 += 32) {
    async16(ag0 + k0, la0);
    async16(ag1 + k0, la1);
    async16(bg0 + k0, lb0);
    async16(bg1 + k0, lb1);
    __syncthreads();
    f16x8 af[4], bf[4];
    #pragma unroll
    for (int i = 0; i < 4; i++)
      af[i] = *(const f16x8*)&tile[(wr * 64 + i * 16 + col) * 32 + quad * 8];
    #pragma unroll
    for (int j = 0; j < 4; j++)
      bf[j] = *(const f16x8*)&tile[4096 + (wc * 64 + j * 16 + col) * 32 + quad * 8];
    #pragma unroll
    for (int i = 0; i < 4; i++)
      #pragma unroll
      for (int j = 0; j < 4; j++)
        acc[i][j] = __builtin_amdgcn_mfma_f32_16x16x32_f16(af[i], bf[j], acc[i][j], 0, 0, 0);
    __syncthreads();
  }

  const int isbf = *flagp;
  if (OUTMODE == 4) {
    #pragma unroll
    for (int i = 0; i < 4; i++) {
      #pragma unroll
      for (int r = 0; r < 4; r++) {
        float v[4]; float ss = 0.f;
        #pragma unroll
        for (int j = 0; j < 4; j++) {
          const int n = bn + wc * 64 + j * 16 + col;
          v[j] = acc[i][j][r] + ldf(bias, bias_off + n, isbf);
          ss += v[j] * v[j];
        }
        ss += __shfl_xor(ss, 1); ss += __shfl_xor(ss, 2);
        ss += __shfl_xor(ss, 4); ss += __shfl_xor(ss, 8);
        const float inv = rsqrtf(fmaxf(ss, 1e-30f));
        const int m = bm + wr * 64 + i * 16 + quad * 4 + r;
        #pragma unroll
        for (int j = 0; j < 4; j++) {
          float u = v[j] * inv;
          if (ACT) u = (u > 0.f) ? u : expm1f(u);
          const int n = bn + wc * 64 + j * 16 + col;
          Cb[(size_t)m * N + n] = f2h(u);
        }
      }
    }
  } else {
    #pragma unroll
    for (int i = 0; i < 4; i++) {
      #pragma unroll
      for (int r = 0; r < 4; r++) {
        const int m = bm + wr * 64 + i * 16 + quad * 4 + r;
        #pragma unroll
        for (int j = 0; j < 4; j++) {
          const int n = bn + wc * 64 + j * 16 + col;
          float c = acc[i][j][r];
          if (OUTMODE == 3) c += ldf(bias, bias_off + m, isbf);
          else              c += ldf(bias, bias_off + n, isbf);
          if (res) c += res[(size_t)m * N + n];
          if (ACT == 1 && OUTMODE != 4) c = fmaxf(c, 0.f);
          if (OUTMODE == 0) {
            Cb[(size_t)m * N + n] = f2h(c);
          } else if (OUTMODE == 1) {
            Cf[(size_t)m * N + n] = c;
            Cb[(size_t)m * N + n] = f2h(c);
          } else {
            const size_t oi = out_base + (size_t)m * N + n;
            if (isbf) ((u16*)Cout)[oi] = f2b(c);
            else      ((float*)Cout)[oi] = c;
          }
        }
      }
    }
  }
}

// ---------------------------------------------------------------------------
// attn_acc_mfma: partial[p][b,n,vi,qi] = sum_{s in 128-chunk p} v[s,vi]*k[s,qi]
// grid (B*H, S/128). LDS-transposed staging (stride 136 = 8*17: 16B-aligned
// fragments, 2-way max read conflicts). MFMA: D[vi][qi] = sum_s Vt[vi][s]*Kt[qi][s].
// ---------------------------------------------------------------------------
#define KT_ 136
__global__ __launch_bounds__(256) void attn_acc_mfma(
    const u16* __restrict__ kbuf, const u16* __restrict__ vbuf,
    float* __restrict__ Apart)
{
  __shared__ u16 ktr[64 * KT_];
  __shared__ u16 vtr[64 * KT_];
  const int bh = blockIdx.x;              // b*H + n
  const int b  = bh >> 3, n = bh & 7;
  const int s0 = blockIdx.y << 7;         // 128 s-rows per block
  const int t = threadIdx.x, lane = t & 63, w = t >> 6;
  const int col = lane & 15, quad = lane >> 4;

  // staging: 128 rows x 16 ushort4 per tensor = 2048 u4; 8 per thread
  #pragma unroll
  for (int u = 0; u < 8; u++) {
    const int flat = u * 256 + t;
    const int row = flat >> 4, q4 = (flat & 15) << 2;
    const size_t g = ((size_t)(s0 + row) * B_ + b) * D_ + n * 64 + q4;
    ushort4 kk = *(const ushort4*)&kbuf[g];
    ushort4 vv = *(const ushort4*)&vbuf[g];
    ktr[(q4+0)*KT_ + row] = kk.x; ktr[(q4+1)*KT_ + row] = kk.y;
    ktr[(q4+2)*KT_ + row] = kk.z; ktr[(q4+3)*KT_ + row] = kk.w;
    vtr[(q4+0)*KT_ + row] = vv.x; vtr[(q4+1)*KT_ + row] = vv.y;
    vtr[(q4+2)*KT_ + row] = vv.z; vtr[(q4+3)*KT_ + row] = vv.w;
  }
  __syncthreads();

  // wave w owns vi-tile w (16 rows of A); j = qi-tile
  f32x4 acc[4] = {};
  #pragma unroll
  for (int ks = 0; ks < 4; ks++) {        // K = 128 = 4 * 32
    const int k0 = ks * 32;
    f16x8 af = *(const f16x8*)&vtr[(w * 16 + col) * KT_ + k0 + quad * 8];
    #pragma unroll
    for (int j = 0; j < 4; j++) {
      f16x8 bf = *(const f16x8*)&ktr[(j * 16 + col) * KT_ + k0 + quad * 8];
      acc[j] = __builtin_amdgcn_mfma_f32_16x16x32_f16(af, bf, acc[j], 0, 0, 0);
    }
  }
  float* Ap = Apart + ((size_t)blockIdx.y * 16 + bh) * 4096;
  #pragma unroll
  for (int j = 0; j < 4; j++)
    #pragma unroll
    for (int r = 0; r < 4; r++) {
      const int vi = w * 16 + quad * 4 + r, qi = j * 16 + col;
      Ap[vi * 64 + qi] = acc[j][r];
    }
}

// ---------------------------------------------------------------------------
// reduce 32 partials -> fp16 A_h[bh*4096 + vi*64 + qi]
// ---------------------------------------------------------------------------
__global__ __launch_bounds__(256) void reduce_A(
    const float* __restrict__ Apart, u16* __restrict__ Ah)
{
  const int i = blockIdx.x * 256 + threadIdx.x;   // 0..65535
  const int bh = i >> 12, idx = i & 4095;
  float s = 0.f;
  #pragma unroll
  for (int p = 0; p < 32; p++)
    s += Apart[((size_t)p * 16 + bh) * 4096 + idx];
  Ah[i] = f2h(s);
}

// ---------------------------------------------------------------------------
// attn_apply_mfma: o[s,vi] = sum_qi q[s,qi] * A_h[vi,qi], in place on qb.
// Pure-register MFMA: both fragments are 16B-contiguous in global memory.
// grid (B*H, S/128); wave w owns 32 s-rows.
// ---------------------------------------------------------------------------
__global__ __launch_bounds__(256) void attn_apply_mfma(
    u16* __restrict__ qo, const u16* __restrict__ Ah)
{
  const int bh = blockIdx.x;
  const int b = bh >> 3, n = bh & 7;
  const int s0 = blockIdx.y << 7;
  const int t = threadIdx.x, lane = t & 63, w = t >> 6;
  const int col = lane & 15, quad = lane >> 4;

  // B fragments: A_h[vi = j*16+col][qi = ks*32 + quad*8 ..+8]
  const u16* Ab_ = Ah + (size_t)bh * 4096;
  f16x8 bf[4][2];
  #pragma unroll
  for (int j = 0; j < 4; j++)
    #pragma unroll
    for (int ks = 0; ks < 2; ks++)
      bf[j][ks] = *(const f16x8*)&Ab_[(j * 16 + col) * 64 + ks * 32 + quad * 8];

  const int srow_base = s0 + w * 32;
  f32x4 acc[2][4] = {};
  #pragma unroll
  for (int i = 0; i < 2; i++) {
    const int s = srow_base + i * 16 + col;
    const u16* qp = qo + ((size_t)s * B_ + b) * D_ + n * 64;
    f16x8 af0 = *(const f16x8*)&qp[quad * 8];
    f16x8 af1 = *(const f16x8*)&qp[32 + quad * 8];
    #pragma unroll
    for (int j = 0; j < 4; j++) {
      acc[i][j] = __builtin_amdgcn_mfma_f32_16x16x32_f16(af0, bf[j][0], acc[i][j], 0, 0, 0);
      acc[i][j] = __builtin_amdgcn_mfma_f32_16x16x32_f16(af1, bf[j][1], acc[i][j], 0, 0, 0);
    }
  }
  #pragma unroll
  for (int i = 0; i < 2; i++)
    #pragma unroll
    for (int r = 0; r < 4; r++) {
      const int s = srow_base + i * 16 + quad * 4 + r;
      u16* op = qo + ((size_t)s * B_ + b) * D_ + n * 64;
      #pragma unroll
      for (int j = 0; j < 4; j++)
        op[j * 16 + col] = f2h(acc[i][j][r]);
    }
}

// ---------------------------------------------------------------------------
// LayerNorm over D=512 per token; reads h fp32, writes h fp32 + hb fp16.
// ---------------------------------------------------------------------------
__global__ __launch_bounds__(256) void ln_k(
    float* __restrict__ h, u16* __restrict__ hb,
    const void* g, size_t g_off, const void* be, size_t be_off, const int* flagp)
{
  const int isbf = *flagp;
  const int m = blockIdx.x, t = threadIdx.x;
  float* p = h + (size_t)m * D_;
  const float x0 = p[t], x1 = p[t + 256];
  __shared__ float red[4];
  float s = x0 + x1;
  #pragma unroll
  for (int off = 32; off >= 1; off >>= 1) s += __shfl_xor(s, off);
  if ((t & 63) == 0) red[t >> 6] = s;
  __syncthreads();
  const float mean = (red[0] + red[1] + red[2] + red[3]) * (1.f / 512.f);
  const float d0 = x0 - mean, d1 = x1 - mean;
  float s2 = d0 * d0 + d1 * d1;
  #pragma unroll
  for (int off = 32; off >= 1; off >>= 1) s2 += __shfl_xor(s2, off);
  __syncthreads();
  if ((t & 63) == 0) red[t >> 6] = s2;
  __syncthreads();
  const float var = (red[0] + red[1] + red[2] + red[3]) * (1.f / 512.f);
  const float sc = rsqrtf(var + 1e-5f);
  const float y0 = d0 * sc * ldf(g, g_off + t, isbf)       + ldf(be, be_off + t, isbf);
  const float y1 = d1 * sc * ldf(g, g_off + t + 256, isbf) + ldf(be, be_off + t + 256, isbf);
  p[t] = y0;       p[t + 256] = y1;
  hb[(size_t)m * D_ + t] = f2h(y0);
  hb[(size_t)m * D_ + t + 256] = f2h(y1);
}

// h/hb[(s*B+b)*D + d] = emb[input[b*S+s]*D + d]
__global__ __launch_bounds__(512) void embed_k(
    const int* __restrict__ inp, const void* emb,
    float* __restrict__ h, u16* __restrict__ hb, const int* flagp)
{
  const int isbf = *flagp;
  const int m = blockIdx.x, t = threadIdx.x;   // m = s*B + b
  const int s = m >> 1, b = m & 1;
  const int tok = inp[b * S_ + s];
  const float v = ldf(emb, (size_t)tok * D_ + t, isbf);
  h[(size_t)m * D_ + t] = v;
  hb[(size_t)m * D_ + t] = f2h(v);
}

// ---------------------------------------------------------------------------
extern "C" void kernel_launch(void* const* d_in, const int* in_sizes, int n_in,
                              void* d_out, int out_size, void* d_ws, size_t ws_size,
                              hipStream_t stream) {
  const int*  inp = (const int*) d_in[0];
  const void* emb = d_in[1];
  const void* Wq  = d_in[2];
  const void* bq  = d_in[3];
  const void* Wk  = d_in[4];
  const void* bk  = d_in[5];
  const void* Wv  = d_in[6];
  const void* bv  = d_in[7];
  const void* Wo  = d_in[8];
  const void* bo  = d_in[9];
  const void* W1  = d_in[10];
  const void* b1  = d_in[11];
  const void* W2  = d_in[12];
  const void* b2  = d_in[13];
  const void* g2  = d_in[14];
  const void* be2 = d_in[15];
  const void* Wfc = d_in[16];
  const void* bfc = d_in[17];

  // workspace layout (bytes)
  char* ws = (char*)d_ws;
  float* h     = (float*)(ws);                    // 16,777,216
  u16*   hb    = (u16*)  (ws + 16777216);         //  8,388,608 (fp16)
  u16*   qb    = (u16*)  (ws + 25165824);         //  8,388,608
  u16*   kb    = (u16*)  (ws + 33554432);         //  8,388,608
  u16*   vb    = (u16*)  (ws + 41943040);         //  8,388,608
  u16*   mid   = qb;                              // 33,554,432 (aliases q,k,v,+)
  float* Apart = (float*)(ws + 58720256);         //  8,388,608 (32 partials)
  u16*   Ah16  = (u16*)  (ws + 67108864);         //    131,072
  u16*   Wc    = (u16*)  (ws + 67239936);         //  6,291,456
  int*   flag  = (int*)  (ws + 73531392);

  detect_dtype<<<1, 64, 0, stream>>>(emb, flag);
  embed_k<<<SB_, 512, 0, stream>>>(inp, emb, h, hb, flag);

  const dim3 gQ(D_ / 128, SB_ / 128);    // (4, 64)
  const dim3 gF(FF_ / 128, SB_ / 128);   // (16, 64)
  const dim3 gFC(S_ / 128, V_ / 128);    // (32, 32)
  const dim3 gAT(B_ * H_, S_ / 128);     // (16, 32)

  for (int l = 0; l < L_; l++) {
    cvt_layer<<<3072, 256, 0, stream>>>(Wq, Wk, Wv, Wo, W1, W2, l, Wc, flag);

    // q = unit(h@Wq^T+bq), k = elu(unit(h@Wk^T+bk)), v = h@Wv^T+bv
    gemm_mfma<0,4><<<gQ, 256, 0, stream>>>(hb, Wc,           1, 0, bq, (size_t)l*D_,  nullptr, nullptr, qb, nullptr, 0, SB_, D_, D_, flag);
    gemm_mfma<1,4><<<gQ, 256, 0, stream>>>(hb, Wc + DD_,     1, 0, bk, (size_t)l*D_,  nullptr, nullptr, kb, nullptr, 0, SB_, D_, D_, flag);
    gemm_mfma<0,0><<<gQ, 256, 0, stream>>>(hb, Wc + 2*DD_,   1, 0, bv, (size_t)l*D_,  nullptr, nullptr, vb, nullptr, 0, SB_, D_, D_, flag);

    attn_acc_mfma<<<gAT, 256, 0, stream>>>(kb, vb, Apart);
    reduce_A<<<256, 256, 0, stream>>>(Apart, Ah16);
    attn_apply_mfma<<<gAT, 256, 0, stream>>>(qb, Ah16);    // qb now holds o

    // h += o @ Wo^T + bo  (writes h fp32 + hb fp16)
    gemm_mfma<0,1><<<gQ, 256, 0, stream>>>(qb, Wc + 3*DD_,   1, 0, bo, (size_t)l*D_,  h, h, hb, nullptr, 0, SB_, D_, D_, flag);
    // mid = relu(h @ W1^T + b1)
    gemm_mfma<1,0><<<gF, 256, 0, stream>>>(hb, Wc + 4*DD_,   1, 0, b1, (size_t)l*FF_, nullptr, nullptr, mid, nullptr, 0, SB_, FF_, D_, flag);
    // h = h + mid @ W2^T + b2 (fp32; hb rewritten by LN)
    gemm_mfma<0,1><<<gQ, 256, 0, stream>>>(mid, Wc + 4*DD_ + FD_, 1, 0, b2, (size_t)l*D_, h, h, hb, nullptr, 0, SB_, D_, FF_, flag);
    ln_k<<<SB_, 256, 0, stream>>>(h, hb, g2, (size_t)l*D_, be2, (size_t)l*D_, flag);
  }

  // FC transposed: out[b][v][s] = Wfc[v,:] . hb[s*2+b,:] + bfc[v]
  cvt1<<<2048, 256, 0, stream>>>(Wfc, Wc, (size_t)V_ * D_, flag);
  gemm_mfma<0,3><<<gFC, 256, 0, stream>>>(Wc, hb, 2, 0, bfc, 0, nullptr, nullptr, nullptr, d_out, 0,                 V_, S_, D_, flag);
  gemm_mfma<0,3><<<gFC, 256, 0, stream>>>(Wc, hb, 2, 1, bfc, 0, nullptr, nullptr, nullptr, d_out, (size_t)V_ * S_, V_, S_, D_, flag);
}